// Round 7
// baseline (163.721 us; speedup 1.0000x reference)
//
#include <hip/hip_runtime.h>
#include <cfloat>

typedef __attribute__((ext_vector_type(8))) short short8;
typedef __attribute__((ext_vector_type(4))) float f32x4;

// Shapes: z_e [32,64,64,64] fp32, codebook [512,64] fp32.
// d_out (fp32 flat): z_q_st [8388608] ++ indices [131072] ++ loss [1].
constexpr int C_DIM    = 64;
constexpr int K_CODES  = 512;
constexpr int HW       = 4096;
constexpr int CHW      = 262144;
constexpr int NPTS     = 131072;
constexpr int ZQ_SIZE  = 8388608;
constexpr int IDX_OFF  = ZQ_SIZE;
constexpr int LOSS_OFF = ZQ_SIZE + NPTS;
constexpr int TILE     = 128;      // points per block
constexpr int CHUNK    = 64;       // codes per staged LDS chunk (8 chunks)
constexpr int NSLOT    = 16;       // candidate slots (8 overflows: margin spans
                                   // ~9 codes for this near-degenerate codebook)
constexpr int ZP       = TILE + 4; // zeC row stride (132 floats, 16B-aligned)
constexpr size_t WS_BF16 = (size_t)K_CODES * C_DIM * 2;   // 65536 B
constexpr size_t WS_NEED = WS_BF16 + (size_t)K_CODES * 4; // + Bs 2048 B

__device__ __forceinline__ unsigned short f32_to_bf16_rne(float f) {
    unsigned u = __float_as_uint(f);
    unsigned r = u + 0x7fffu + ((u >> 16) & 1u);
    return (unsigned short)(r >> 16);
}

// numpy pairwise_sum of 64 fp32 squares (8-accumulator scheme) — bit-exact
// vs np.sum(a*a, axis=1) for a 64-long row.
template <int STRIDE>
__device__ __forceinline__ float np_sumsq64(const float* __restrict__ a) {
    float r[8];
#pragma unroll
    for (int j = 0; j < 8; ++j) { const float v = a[j * STRIDE]; r[j] = __fmul_rn(v, v); }
#pragma unroll
    for (int i = 8; i < 64; i += 8)
#pragma unroll
        for (int j = 0; j < 8; ++j) {
            const float v = a[(i + j) * STRIDE];
            r[j] = __fadd_rn(r[j], __fmul_rn(v, v));
        }
    return __fadd_rn(
        __fadd_rn(__fadd_rn(r[0], r[1]), __fadd_rn(r[2], r[3])),
        __fadd_rn(__fadd_rn(r[4], r[5]), __fadd_rn(r[6], r[7])));
}

__global__ void vq_zero(float* __restrict__ out) { out[LOSS_OFF] = 0.0f; }

// Prep: bf16 codebook -> ws, Bs (numpy pairwise) -> ws, zero loss slot.
__global__ void vq_prep(const float* __restrict__ cb, unsigned short* __restrict__ wsb,
                        float* __restrict__ wsB, float* __restrict__ out) {
    const int gid = blockIdx.x * 256 + threadIdx.x;   // grid covers 512*64
    wsb[gid] = f32_to_bf16_rne(cb[gid]);
    if (gid < K_CODES) wsB[gid] = np_sumsq64<1>(cb + gid * C_DIM);
    if (gid == 0) out[LOSS_OFF] = 0.0f;
}

__global__ __launch_bounds__(256, 4) void vq_idx(const float* __restrict__ ze,
                                                 const float* __restrict__ cb,
                                                 float* __restrict__ out,
                                                 const unsigned short* __restrict__ wsb,
                                                 const float* __restrict__ wsB,
                                                 int use_ws)
{
    // zeC: the block's z_e tile [channel][point], staged ONCE with coalesced
    // float4 loads. All later z_e accesses (As, afr, rescore, rescue,
    // epilogue) read LDS — z_e global traffic drops to exactly 1x and the
    // cold strided-load latency chains disappear. Stride 132: rows 16B-aligned
    // for ds_read_b128, all access patterns <=2-way on banks.
    __shared__ __align__(16) float zeC[C_DIM][ZP];     // 33792 B
    // eh: CHUNK code rows x 64 bf16, XOR-swizzled 16B slots (slot s of row r
    // at s^(r&7)); bit-exact + conflict-free in 6 prior rounds.
    __shared__ unsigned short eh[CHUNK * C_DIM];       //  8192 B
    __shared__ float  BsL[K_CODES];                    //  2048 B
    __shared__ float  As[TILE];                        //   512 B
    __shared__ unsigned short cand[TILE * NSLOT];      //  4096 B
    __shared__ int    cnt[TILE];                       //   512 B
    __shared__ int    bestk[TILE];                     //   512 B
    __shared__ double lred[4];                         // total ~48.5 KiB -> 3 blk/CU

    const int tid  = threadIdx.x;          // 0..255 (4 waves)
    const int lane = tid & 63, w = tid >> 6;
    const int quad = lane >> 4, l15 = lane & 15;
    const int n0   = blockIdx.x * TILE;    // grid = 1024
    const int b    = n0 >> 12, hw0 = n0 & (HW - 1);
    const float* zebase = ze + b * CHW + hw0;

    // ---- stage zeC (coalesced, z_e's only global read) + BsL ----
#pragma unroll
    for (int i = 0; i < 8; ++i) {
        const int idx = tid + 256 * i;                // 2048 float4 tasks
        const int c = idx >> 5, q = idx & 31;
        const float4 v = *(const float4*)(zebase + c * HW + 4 * q);
        *(float4*)&zeC[c][4 * q] = v;
    }
    if (use_ws) { for (int k = tid; k < K_CODES; k += 256) BsL[k] = wsB[k]; }
    else        { for (int k = tid; k < K_CODES; k += 256) BsL[k] = np_sumsq64<1>(cb + k * C_DIM); }
    if (tid < TILE) cnt[tid] = 0;
    __syncthreads();

    auto stage = [&](int ch) {   // CHUNK=64 rows; 4 threads x 2 slots per row
        const int row = tid >> 2, sl0 = (tid & 3) * 2;
        uint4* base = (uint4*)eh;      // 16 B units: row*8 + physical slot
        if (use_ws) {
            const uint4* src = (const uint4*)(wsb + (size_t)(ch * CHUNK + row) * C_DIM);
#pragma unroll
            for (int t = 0; t < 2; ++t) {
                const int s = sl0 + t;
                base[row * 8 + (s ^ (row & 7))] = src[s];
            }
        } else {
            const float4* src = (const float4*)(cb + (size_t)(ch * CHUNK + row) * C_DIM);
#pragma unroll
            for (int t = 0; t < 2; ++t) {
                const int s = sl0 + t;
                const float4 f0 = src[2 * s], f1 = src[2 * s + 1];
                uint4 o;
                o.x = (unsigned)f32_to_bf16_rne(f0.x) | ((unsigned)f32_to_bf16_rne(f0.y) << 16);
                o.y = (unsigned)f32_to_bf16_rne(f0.z) | ((unsigned)f32_to_bf16_rne(f0.w) << 16);
                o.z = (unsigned)f32_to_bf16_rne(f1.x) | ((unsigned)f32_to_bf16_rne(f1.y) << 16);
                o.w = (unsigned)f32_to_bf16_rne(f1.z) | ((unsigned)f32_to_bf16_rne(f1.w) << 16);
                base[row * 8 + (s ^ (row & 7))] = o;
            }
        }
    };

    // ---- As (bit-exact pairwise chain, now from LDS) + stage chunk 0 ----
    if (tid < TILE) As[tid] = np_sumsq64<ZP>(&zeC[0][tid]);
    stage(0);
    __syncthreads();

    // A fragments (bf16 RNE of x) from zeC; wave w owns points w*32..w*32+31.
    short8 afr[2][2];
    float  A_pt[2][4], thr[2][4], runmin[2][4];
#pragma unroll
    for (int rt = 0; rt < 2; ++rt) {
        const int pt = w * 32 + rt * 16 + l15;
#pragma unroll
        for (int kc = 0; kc < 2; ++kc) {
            union { unsigned short s[8]; short8 v; } u;
#pragma unroll
            for (int j = 0; j < 8; ++j) {
                const int c = kc * 32 + quad * 8 + j;
                u.s[j] = f32_to_bf16_rne(zeC[c][pt]);
            }
            afr[rt][kc] = u.v;
        }
#pragma unroll
        for (int r = 0; r < 4; ++r) {
            A_pt[rt][r]   = As[w * 32 + rt * 16 + quad * 4 + r];
            runmin[rt][r] = FLT_MAX;
        }
    }

    // ---- pass 1: streaming approx-min over all 512 codes (8 chunks) ----
    for (int ch = 0; ch < 8; ++ch) {
        const uint4* ebase = (const uint4*)eh;
#pragma unroll
        for (int tile = 0; tile < 4; ++tile) {
            const int cl = tile * 16 + l15;           // code row within chunk
            const short8 b0 = *(const short8*)&ebase[cl * 8 + ((quad    ) ^ (cl & 7))];
            const short8 b1 = *(const short8*)&ebase[cl * 8 + ((quad + 4) ^ (cl & 7))];
            const float bs = BsL[ch * CHUNK + cl];
#pragma unroll
            for (int rt = 0; rt < 2; ++rt) {
                f32x4 acc = {0.f, 0.f, 0.f, 0.f};
                acc = __builtin_amdgcn_mfma_f32_16x16x32_bf16(afr[rt][0], b0, acc, 0, 0, 0);
                acc = __builtin_amdgcn_mfma_f32_16x16x32_bf16(afr[rt][1], b1, acc, 0, 0, 0);
#pragma unroll
                for (int r = 0; r < 4; ++r) {
                    const float D = fmaf(-2.f, acc[r], __fadd_rn(A_pt[rt][r], bs));
                    runmin[rt][r] = fminf(runmin[rt][r], D);
                }
            }
        }
        if (ch < 7) { __syncthreads(); stage(ch + 1); __syncthreads(); }
    }
    // cross-lane min over the 16 l15-lanes sharing each point; margin 3x the
    // rigorous bf16-vs-chain error bound.
#pragma unroll
    for (int rt = 0; rt < 2; ++rt)
#pragma unroll
        for (int r = 0; r < 4; ++r) {
            float v = runmin[rt][r];
#pragma unroll
            for (int m = 1; m < 16; m <<= 1) v = fminf(v, __shfl_xor(v, m, 64));
            thr[rt][r] = v + (4e-4f * sqrtf(A_pt[rt][r]) + 3e-4f);
        }

    // ---- pass 2: collect candidates under the global threshold ----
    // Chunk 7 is still resident (no eh writes since its last read): scan it
    // first, then restage 0..6. Candidate order is irrelevant (strict-min
    // with lowest-k tiebreak is order-independent).
    auto scan_push = [&](int ch) {
        const uint4* ebase = (const uint4*)eh;
#pragma unroll
        for (int tile = 0; tile < 4; ++tile) {
            const int cl = tile * 16 + l15;
            const short8 b0 = *(const short8*)&ebase[cl * 8 + ((quad    ) ^ (cl & 7))];
            const short8 b1 = *(const short8*)&ebase[cl * 8 + ((quad + 4) ^ (cl & 7))];
            const float bs = BsL[ch * CHUNK + cl];
#pragma unroll
            for (int rt = 0; rt < 2; ++rt) {
                f32x4 acc = {0.f, 0.f, 0.f, 0.f};
                acc = __builtin_amdgcn_mfma_f32_16x16x32_bf16(afr[rt][0], b0, acc, 0, 0, 0);
                acc = __builtin_amdgcn_mfma_f32_16x16x32_bf16(afr[rt][1], b1, acc, 0, 0, 0);
#pragma unroll
                for (int r = 0; r < 4; ++r) {
                    const float D = fmaf(-2.f, acc[r], __fadd_rn(A_pt[rt][r], bs));
                    if (D <= thr[rt][r]) {
                        const int pt = w * 32 + rt * 16 + quad * 4 + r;
                        const int p = atomicAdd(&cnt[pt], 1);
                        if (p < NSLOT) cand[pt * NSLOT + p] = (unsigned short)(ch * CHUNK + cl);
                    }
                }
            }
        }
    };
    scan_push(7);                      // eh already holds chunk 7
    for (int ch = 0; ch < 7; ++ch) {
        __syncthreads(); stage(ch); __syncthreads();
        scan_push(ch);
    }
    __syncthreads();

    // ---- exact rescore, 2 threads per point (parity split over candidates;
    // strict-min + lowest-k combine is order-independent -> identical result
    // to the serial scan). z_e reads now from LDS. ----
    {
        const int pt = tid >> 1, j0 = tid & 1;
        const int c = cnt[pt];
        if (c <= NSLOT) {
            const float Av = As[pt];
            float bD = FLT_MAX; int bK = K_CODES;
            for (int i = j0; i < c; i += 2) {
                const int k = cand[pt * NSLOT + i];
                const float* er = cb + k * C_DIM;
                float M = 0.f;
#pragma unroll
                for (int cc = 0; cc < 64; ++cc) M = fmaf(zeC[cc][pt], er[cc], M);
                const float D = fmaf(-2.f, M, __fadd_rn(Av, BsL[k]));
                if (D < bD || (D == bD && k < bK)) { bD = D; bK = k; }
            }
            const float oD = __shfl_xor(bD, 1, 64);
            const int   oK = __shfl_xor(bK, 1, 64);
            if (oD < bD || (oD == bD && oK < bK)) { bD = oD; bK = oK; }
            if (j0 == 0) { bestk[pt] = bK; out[IDX_OFF + n0 + pt] = (float)bK; }
        }
        // overflow points handled below by the whole wave
    }
    __syncthreads();

    // ---- overflow rescue: wave-cooperative exact full scan (rare) ----
    // Lexicographic (D,k) min-reduce == ascending serial strict-< scan.
    for (int pp = 0; pp < 32; ++pp) {
        const int pt = w * 32 + pp;
        if (cnt[pt] <= NSLOT) continue;            // wave-uniform broadcast read
        const float Av = As[pt];
        float bD = FLT_MAX; int bK = K_CODES;
        for (int k = lane; k < K_CODES; k += 64) {
            const float* er = cb + k * C_DIM;
            float M = 0.f;
#pragma unroll
            for (int cc = 0; cc < 64; ++cc) M = fmaf(zeC[cc][pt], er[cc], M);
            const float D = fmaf(-2.f, M, __fadd_rn(Av, BsL[k]));
            if (D < bD || (D == bD && k < bK)) { bD = D; bK = k; }
        }
#pragma unroll
        for (int off = 1; off < 64; off <<= 1) {
            const float oD = __shfl_xor(bD, off, 64);
            const int   oK = __shfl_xor(bK, off, 64);
            if (oD < bD || (oD == bD && oK < bK)) { bD = oD; bK = oK; }
        }
        if (lane == 0) { bestk[pt] = bK; out[IDX_OFF + n0 + pt] = (float)bK; }
    }
    __syncthreads();

    // ---- epilogue: z_q_st (ref formula bitwise) + loss; z_e from LDS ----
    double ls = 0.0;
#pragma unroll
    for (int it = 0; it < 8; ++it) {
        const int task = tid + 256 * it;          // 2048 tasks = 64 c x 32 quads
        const int c = task >> 5, q = task & 31;
        const float4 xz = *(const float4*)&zeC[c][4 * q];   // bitwise == global
        float o[4];
#pragma unroll
        for (int j = 0; j < 4; ++j) {
            const int k = bestk[4 * q + j];
            const float ev = cb[k * C_DIM + c];   // gather, L1/L2-hot
            const float xv = (j == 0) ? xz.x : (j == 1) ? xz.y : (j == 2) ? xz.z : xz.w;
            const float d = __fsub_rn(ev, xv);    // ref: z_q - z_e
            o[j] = __fadd_rn(xv, d);              // ref: z_e + (...)
            ls = fma((double)d, (double)d, ls);
        }
        *(float4*)(out + b * CHW + c * HW + hw0 + 4 * q) = make_float4(o[0], o[1], o[2], o[3]);
    }
#pragma unroll
    for (int off = 32; off > 0; off >>= 1) ls += __shfl_xor(ls, off, 64);
    if ((tid & 63) == 0) lred[w] = ls;
    __syncthreads();
    if (tid == 0)
        atomicAdd(out + LOSS_OFF,
                  (float)((lred[0] + lred[1] + lred[2] + lred[3]) * (1.25 / (double)ZQ_SIZE)));
}

extern "C" void kernel_launch(void* const* d_in, const int* in_sizes, int n_in,
                              void* d_out, int out_size, void* d_ws, size_t ws_size,
                              hipStream_t stream) {
    (void)in_sizes; (void)n_in; (void)out_size;
    const float* ze = (const float*)d_in[0];
    const float* cb = (const float*)d_in[1];
    float* out = (float*)d_out;
    const int use_ws = (ws_size >= WS_NEED) ? 1 : 0;
    unsigned short* wsb = (unsigned short*)d_ws;
    float* wsB = (float*)((char*)d_ws + WS_BF16);

    if (use_ws) vq_prep<<<(K_CODES * C_DIM) / 256, 256, 0, stream>>>(cb, wsb, wsB, out);
    else        vq_zero<<<1, 1, 0, stream>>>(out);
    vq_idx<<<NPTS / TILE, 256, 0, stream>>>(ze, cb, out, wsb, wsB, use_ws);
}

// Round 8
// 136.769 us; speedup vs baseline: 1.1971x; 1.1971x over previous
//
#include <hip/hip_runtime.h>
#include <cfloat>

typedef __attribute__((ext_vector_type(8))) short short8;
typedef __attribute__((ext_vector_type(4))) float f32x4;

// Shapes: z_e [32,64,64,64] fp32, codebook [512,64] fp32.
// d_out (fp32 flat): z_q_st [8388608] ++ indices [131072] ++ loss [1].
constexpr int C_DIM    = 64;
constexpr int K_CODES  = 512;
constexpr int HW       = 4096;
constexpr int CHW      = 262144;
constexpr int NPTS     = 131072;
constexpr int ZQ_SIZE  = 8388608;
constexpr int IDX_OFF  = ZQ_SIZE;
constexpr int LOSS_OFF = ZQ_SIZE + NPTS;
constexpr int TILE     = 128;      // points per block
constexpr int CHUNK    = 256;      // codes per staged LDS chunk (2 chunks)
constexpr int NSLOT    = 16;       // margin spans ~6-9 codes here; 8 overflows
constexpr size_t WS_BF16 = (size_t)K_CODES * C_DIM * 2;   // 65536 B
constexpr size_t WS_NEED = WS_BF16 + (size_t)K_CODES * 4; // + Bs 2048 B

__device__ __forceinline__ unsigned short f32_to_bf16_rne(float f) {
    unsigned u = __float_as_uint(f);
    unsigned r = u + 0x7fffu + ((u >> 16) & 1u);
    return (unsigned short)(r >> 16);
}

// numpy pairwise_sum of 64 fp32 squares (8-accumulator scheme) — bit-exact
// vs np.sum(a*a, axis=1) for a 64-long row.
template <int STRIDE>
__device__ __forceinline__ float np_sumsq64(const float* __restrict__ a) {
    float r[8];
#pragma unroll
    for (int j = 0; j < 8; ++j) { const float v = a[j * STRIDE]; r[j] = __fmul_rn(v, v); }
#pragma unroll
    for (int i = 8; i < 64; i += 8)
#pragma unroll
        for (int j = 0; j < 8; ++j) {
            const float v = a[(i + j) * STRIDE];
            r[j] = __fadd_rn(r[j], __fmul_rn(v, v));
        }
    return __fadd_rn(
        __fadd_rn(__fadd_rn(r[0], r[1]), __fadd_rn(r[2], r[3])),
        __fadd_rn(__fadd_rn(r[4], r[5]), __fadd_rn(r[6], r[7])));
}

// Half of the 8-accumulator pairwise scheme (accumulators j0*4..j0*4+3),
// stride HW. fadd of the two halves == np_sumsq64<HW> bit-exactly (the
// pairwise tree splits at the 4+4 boundary). Verified absmax=0 in r1/r2.
__device__ __forceinline__ float np_sumsq64_half_hw(const float* __restrict__ a, int j0) {
    float r[4];
#pragma unroll
    for (int jj = 0; jj < 4; ++jj) {
        const float v = a[(j0 * 4 + jj) * HW];
        r[jj] = __fmul_rn(v, v);
    }
#pragma unroll
    for (int i = 8; i < 64; i += 8)
#pragma unroll
        for (int jj = 0; jj < 4; ++jj) {
            const float v = a[(i + j0 * 4 + jj) * HW];
            r[jj] = __fadd_rn(r[jj], __fmul_rn(v, v));
        }
    return __fadd_rn(__fadd_rn(r[0], r[1]), __fadd_rn(r[2], r[3]));
}

__global__ void vq_zero(float* __restrict__ out) { out[LOSS_OFF] = 0.0f; }

// Prep: bf16 codebook -> ws, Bs (numpy pairwise) -> ws, zero loss slot.
__global__ void vq_prep(const float* __restrict__ cb, unsigned short* __restrict__ wsb,
                        float* __restrict__ wsB, float* __restrict__ out) {
    const int gid = blockIdx.x * 256 + threadIdx.x;   // grid covers 512*64
    wsb[gid] = f32_to_bf16_rne(cb[gid]);
    if (gid < K_CODES) wsB[gid] = np_sumsq64<1>(cb + gid * C_DIM);
    if (gid == 0) out[LOSS_OFF] = 0.0f;
}

__global__ __launch_bounds__(256, 4) void vq_idx(const float* __restrict__ ze,
                                                 const float* __restrict__ cb,
                                                 float* __restrict__ out,
                                                 const unsigned short* __restrict__ wsb,
                                                 const float* __restrict__ wsB,
                                                 int use_ws)
{
    // eh: CHUNK code rows x 64 bf16, dense, XOR-swizzled in 16 B slots (slot s
    // of row r at s^(r&7)); bit-exact + conflict-free across 7 rounds.
    // LDS total 40960 B -> exactly 4 blocks/CU (r6-measured 34.8% occupancy;
    // 50 KB drops to 3 blocks and regresses 1.6x — r7).
    __shared__ unsigned short eh[CHUNK * C_DIM];       // 32768 B
    __shared__ float  BsL[K_CODES];                    //  2048 B
    __shared__ float  As[TILE];                        //   512 B
    __shared__ unsigned short cand[TILE * NSLOT];      //  4096 B
    __shared__ int    cnt[TILE];                       //   512 B
    __shared__ int    bestk[TILE];                     //   512 B
    __shared__ double lred[4];                         // total 40.4 KiB

    const int tid  = threadIdx.x;          // 0..255 (4 waves)
    const int lane = tid & 63, w = tid >> 6;
    const int quad = lane >> 4, l15 = lane & 15;
    const int n0   = blockIdx.x * TILE;    // grid = 1024
    const int b    = n0 >> 12, hw0 = n0 & (HW - 1);
    const float* zebase = ze + b * CHW + hw0;

    auto stage = [&](int ch) {   // 256 threads: one 128 B code row each, swizzled
        const int row = tid;
        uint4* base = (uint4*)eh;      // 16 B units: row*8 + physical slot
        if (use_ws) {
            const uint4* src = (const uint4*)(wsb + (size_t)(ch * CHUNK + row) * C_DIM);
#pragma unroll
            for (int s = 0; s < 8; ++s) base[row * 8 + (s ^ (row & 7))] = src[s];
        } else {
            const float4* src = (const float4*)(cb + (size_t)(ch * CHUNK + row) * C_DIM);
#pragma unroll
            for (int s = 0; s < 8; ++s) {
                const float4 f0 = src[2 * s], f1 = src[2 * s + 1];
                uint4 o;
                o.x = (unsigned)f32_to_bf16_rne(f0.x) | ((unsigned)f32_to_bf16_rne(f0.y) << 16);
                o.y = (unsigned)f32_to_bf16_rne(f0.z) | ((unsigned)f32_to_bf16_rne(f0.w) << 16);
                o.z = (unsigned)f32_to_bf16_rne(f1.x) | ((unsigned)f32_to_bf16_rne(f1.y) << 16);
                o.w = (unsigned)f32_to_bf16_rne(f1.z) | ((unsigned)f32_to_bf16_rne(f1.w) << 16);
                base[row * 8 + (s ^ (row & 7))] = o;
            }
        }
    };

    // ---- merged prologue: ALL independent memory issued with no barriers ----
    // BsL loads, chunk-0 staging, As strided loads (2 threads/point, exact
    // pairwise split), afr loads (L1-hot behind As) share the VMEM queue —
    // one latency wait instead of four.
    if (use_ws) { for (int k = tid; k < K_CODES; k += 256) BsL[k] = wsB[k]; }
    else        { for (int k = tid; k < K_CODES; k += 256) BsL[k] = np_sumsq64<1>(cb + k * C_DIM); }
    if (tid < TILE) cnt[tid] = 0;
    stage(0);
    {
        const int ptA = tid >> 1, j0 = tid & 1;
        const float p = np_sumsq64_half_hw(zebase + ptA, j0);
        const float o = __shfl_xor(p, 1, 64);
        if (j0 == 0) As[ptA] = __fadd_rn(p, o);   // == np_sumsq64<HW> bitwise
    }

    // A fragments (bf16 RNE of x): A[m=lane&15][k=quad*8+j]; wave w owns
    // points w*32 .. w*32+31 (rt in {0,1}).
    short8 afr[2][2];
    float  A_pt[2][4], thr[2][4], runmin[2][4];
#pragma unroll
    for (int rt = 0; rt < 2; ++rt) {
        const int pt = w * 32 + rt * 16 + l15;
#pragma unroll
        for (int kc = 0; kc < 2; ++kc) {
            union { unsigned short s[8]; short8 v; } u;
#pragma unroll
            for (int j = 0; j < 8; ++j) {
                const int c = kc * 32 + quad * 8 + j;
                u.s[j] = f32_to_bf16_rne(zebase[c * HW + pt]);
            }
            afr[rt][kc] = u.v;
        }
#pragma unroll
        for (int r = 0; r < 4; ++r) runmin[rt][r] = FLT_MAX;
    }
    __syncthreads();                      // As + eh(ch0) + BsL all visible
#pragma unroll
    for (int rt = 0; rt < 2; ++rt)
#pragma unroll
        for (int r = 0; r < 4; ++r)
            A_pt[rt][r] = As[w * 32 + rt * 16 + quad * 4 + r];

    // ---- pass 1: streaming approx-min over all 512 codes (2 chunks) ----
    for (int ch = 0; ch < 2; ++ch) {
        if (ch) { __syncthreads(); stage(ch); __syncthreads(); }
        const uint4* ebase = (const uint4*)eh;
#pragma unroll 4
        for (int tile = 0; tile < 16; ++tile) {
            const int cl = tile * 16 + l15;           // code row within chunk
            const short8 b0 = *(const short8*)&ebase[cl * 8 + ((quad    ) ^ (cl & 7))];
            const short8 b1 = *(const short8*)&ebase[cl * 8 + ((quad + 4) ^ (cl & 7))];
            const float bs = BsL[ch * CHUNK + cl];
#pragma unroll
            for (int rt = 0; rt < 2; ++rt) {
                f32x4 acc = {0.f, 0.f, 0.f, 0.f};
                acc = __builtin_amdgcn_mfma_f32_16x16x32_bf16(afr[rt][0], b0, acc, 0, 0, 0);
                acc = __builtin_amdgcn_mfma_f32_16x16x32_bf16(afr[rt][1], b1, acc, 0, 0, 0);
#pragma unroll
                for (int r = 0; r < 4; ++r) {
                    const float D = fmaf(-2.f, acc[r], __fadd_rn(A_pt[rt][r], bs));
                    runmin[rt][r] = fminf(runmin[rt][r], D);
                }
            }
        }
    }
    // cross-lane min over the 16 l15-lanes sharing each point; margin 3x the
    // rigorous bf16-vs-chain error bound.
#pragma unroll
    for (int rt = 0; rt < 2; ++rt)
#pragma unroll
        for (int r = 0; r < 4; ++r) {
            float v = runmin[rt][r];
#pragma unroll
            for (int m = 1; m < 16; m <<= 1) v = fminf(v, __shfl_xor(v, m, 64));
            thr[rt][r] = v + (4e-4f * sqrtf(A_pt[rt][r]) + 3e-4f);
        }

    // ---- pass 2: collect candidates under the global threshold ----
    // Chunk 1 still resident (no eh writes since its last read): scan first,
    // then restage chunk 0. Candidate order irrelevant (strict-min + lowest-k
    // tiebreak is order-independent).
    auto scan_push = [&](int ch) {
        const uint4* ebase = (const uint4*)eh;
#pragma unroll 4
        for (int tile = 0; tile < 16; ++tile) {
            const int cl = tile * 16 + l15;
            const short8 b0 = *(const short8*)&ebase[cl * 8 + ((quad    ) ^ (cl & 7))];
            const short8 b1 = *(const short8*)&ebase[cl * 8 + ((quad + 4) ^ (cl & 7))];
            const float bs = BsL[ch * CHUNK + cl];
#pragma unroll
            for (int rt = 0; rt < 2; ++rt) {
                f32x4 acc = {0.f, 0.f, 0.f, 0.f};
                acc = __builtin_amdgcn_mfma_f32_16x16x32_bf16(afr[rt][0], b0, acc, 0, 0, 0);
                acc = __builtin_amdgcn_mfma_f32_16x16x32_bf16(afr[rt][1], b1, acc, 0, 0, 0);
#pragma unroll
                for (int r = 0; r < 4; ++r) {
                    const float D = fmaf(-2.f, acc[r], __fadd_rn(A_pt[rt][r], bs));
                    if (D <= thr[rt][r]) {
                        const int pt = w * 32 + rt * 16 + quad * 4 + r;
                        const int p = atomicAdd(&cnt[pt], 1);
                        if (p < NSLOT) cand[pt * NSLOT + p] = (unsigned short)(ch * CHUNK + cl);
                    }
                }
            }
        }
    };
    scan_push(1);                      // eh already holds chunk 1
    __syncthreads(); stage(0); __syncthreads();
    scan_push(0);
    __syncthreads();

    // ---- exact rescore, 2 threads/point (parity split; strict-min + lowest-k
    // combine is order-independent -> identical to the serial scan). z_e reads
    // are L1-hot (touched by As/afr). ----
    {
        const int pt = tid >> 1, j0 = tid & 1;
        const int c = cnt[pt];
        if (c <= NSLOT) {
            const float Av = As[pt];
            float bD = FLT_MAX; int bK = K_CODES;
            for (int i = j0; i < c; i += 2) {
                const int k = cand[pt * NSLOT + i];
                const float* er = cb + k * C_DIM;
                float M = 0.f;
#pragma unroll
                for (int cc = 0; cc < 64; ++cc) M = fmaf(zebase[cc * HW + pt], er[cc], M);
                const float D = fmaf(-2.f, M, __fadd_rn(Av, BsL[k]));
                if (D < bD || (D == bD && k < bK)) { bD = D; bK = k; }
            }
            const float oD = __shfl_xor(bD, 1, 64);
            const int   oK = __shfl_xor(bK, 1, 64);
            if (oD < bD || (oD == bD && oK < bK)) { bD = oD; bK = oK; }
            if (j0 == 0) { bestk[pt] = bK; out[IDX_OFF + n0 + pt] = (float)bK; }
        }
        // overflow points handled below by the whole wave
    }
    __syncthreads();

    // ---- overflow rescue: wave-cooperative exact full scan (rare) ----
    // Lexicographic (D,k) min-reduce == ascending serial strict-< scan.
    for (int pp = 0; pp < 32; ++pp) {
        const int pt = w * 32 + pp;
        if (cnt[pt] <= NSLOT) continue;            // wave-uniform broadcast read
        const float Av = As[pt];
        float bD = FLT_MAX; int bK = K_CODES;
        for (int k = lane; k < K_CODES; k += 64) {
            const float* er = cb + k * C_DIM;
            float M = 0.f;
#pragma unroll
            for (int cc = 0; cc < 64; ++cc) M = fmaf(zebase[cc * HW + pt], er[cc], M);
            const float D = fmaf(-2.f, M, __fadd_rn(Av, BsL[k]));
            if (D < bD || (D == bD && k < bK)) { bD = D; bK = k; }
        }
#pragma unroll
        for (int off = 1; off < 64; off <<= 1) {
            const float oD = __shfl_xor(bD, off, 64);
            const int   oK = __shfl_xor(bK, off, 64);
            if (oD < bD || (oD == bD && oK < bK)) { bD = oD; bK = oK; }
        }
        if (lane == 0) { bestk[pt] = bK; out[IDX_OFF + n0 + pt] = (float)bK; }
    }
    __syncthreads();

    // ---- epilogue: z_q_st (ref formula bitwise) + loss, float4 along hw ----
    double ls = 0.0;
#pragma unroll
    for (int it = 0; it < 8; ++it) {
        const int task = tid + 256 * it;          // 2048 tasks = 64 c x 32 quads
        const int c = task >> 5, q = task & 31;
        const float4 xz = *(const float4*)(zebase + c * HW + 4 * q);
        float o[4];
#pragma unroll
        for (int j = 0; j < 4; ++j) {
            const int k = bestk[4 * q + j];
            const float ev = cb[k * C_DIM + c];   // gather, L1/L2-hot
            const float xv = (j == 0) ? xz.x : (j == 1) ? xz.y : (j == 2) ? xz.z : xz.w;
            const float d = __fsub_rn(ev, xv);    // ref: z_q - z_e
            o[j] = __fadd_rn(xv, d);              // ref: z_e + (...)
            ls = fma((double)d, (double)d, ls);
        }
        *(float4*)(out + b * CHW + c * HW + hw0 + 4 * q) = make_float4(o[0], o[1], o[2], o[3]);
    }
#pragma unroll
    for (int off = 32; off > 0; off >>= 1) ls += __shfl_xor(ls, off, 64);
    if ((tid & 63) == 0) lred[w] = ls;
    __syncthreads();
    if (tid == 0)
        atomicAdd(out + LOSS_OFF,
                  (float)((lred[0] + lred[1] + lred[2] + lred[3]) * (1.25 / (double)ZQ_SIZE)));
}

extern "C" void kernel_launch(void* const* d_in, const int* in_sizes, int n_in,
                              void* d_out, int out_size, void* d_ws, size_t ws_size,
                              hipStream_t stream) {
    (void)in_sizes; (void)n_in; (void)out_size;
    const float* ze = (const float*)d_in[0];
    const float* cb = (const float*)d_in[1];
    float* out = (float*)d_out;
    const int use_ws = (ws_size >= WS_NEED) ? 1 : 0;
    unsigned short* wsb = (unsigned short*)d_ws;
    float* wsB = (float*)((char*)d_ws + WS_BF16);

    if (use_ws) vq_prep<<<(K_CODES * C_DIM) / 256, 256, 0, stream>>>(cb, wsb, wsB, out);
    else        vq_zero<<<1, 1, 0, stream>>>(out);
    vq_idx<<<NPTS / TILE, 256, 0, stream>>>(ze, cb, out, wsb, wsB, use_ws);
}